// Round 2
// baseline (812.123 us; speedup 1.0000x reference)
//
#include <hip/hip_runtime.h>

#define BSZ_  4
#define SEQ_  1024
#define NH_   32
#define NKVH_ 8
#define HD_   128
#define DIM_  4096
#define NTOK_ (BSZ_ * SEQ_)   // 4096 tokens
#define QKVW_ 6144            // fused QKV output width (u16 elems per token)

typedef float  floatx4  __attribute__((ext_vector_type(4)));
typedef float  floatx16 __attribute__((ext_vector_type(16)));
typedef __bf16 bf16x8   __attribute__((ext_vector_type(8)));
typedef unsigned short ushortx8 __attribute__((ext_vector_type(8)));

__device__ __forceinline__ float fast_exp2(float x) {
  return __builtin_amdgcn_exp2f(x);   // v_exp_f32 (computes 2^x natively)
}

__device__ __forceinline__ unsigned short f2bf_bits(float f) {
  unsigned int u = __float_as_uint(f);
  u += 0x7FFFu + ((u >> 16) & 1u);   // round-to-nearest-even
  return (unsigned short)(u >> 16);
}
__device__ __forceinline__ unsigned int pack_bf2_rne(float lo, float hi_) {
  return (unsigned int)f2bf_bits(lo) | ((unsigned int)f2bf_bits(hi_) << 16);
}
// truncating pack of two fp32 -> bf16x2 (one v_perm_b32)
__device__ __forceinline__ unsigned int pack_bf2_trunc(float lo, float hi_) {
  return __builtin_amdgcn_perm(__float_as_uint(hi_), __float_as_uint(lo), 0x07060302u);
}

// async global->LDS, 16B per lane; LDS dest = wave-uniform base + lane*16
__device__ __forceinline__ void gld16(const void* g, void* l) {
  __builtin_amdgcn_global_load_lds(
      (const __attribute__((address_space(1))) void*)g,
      (__attribute__((address_space(3))) void*)l, 16, 0, 0);
}

// ---------------------------------------------------------------------------
// fp32 -> bf16 convert (contiguous).
// ---------------------------------------------------------------------------
__global__ __launch_bounds__(256)
void xconv(const float* __restrict__ X, unsigned short* __restrict__ XB)
{
  size_t i = ((size_t)blockIdx.x * 256 + threadIdx.x) * 4;
  float4 v = *(const float4*)&X[i];
  ushort4 o;
  o.x = f2bf_bits(v.x); o.y = f2bf_bits(v.y);
  o.z = f2bf_bits(v.z); o.w = f2bf_bits(v.w);
  *(ushort4*)&XB[i] = o;
}

// ---------------------------------------------------------------------------
// Weight transpose-convert: W[K][N] fp32 -> WT[N][K] bf16. 32x32 tiles.
// ---------------------------------------------------------------------------
__global__ __launch_bounds__(256)
void wtrans(const float* __restrict__ W, unsigned short* __restrict__ WT,
            int K, int N)
{
  __shared__ unsigned short T[32][36];
  const int k0 = blockIdx.y * 32, n0 = blockIdx.x * 32;
  const int t = threadIdx.x;
  {
    int kr = t >> 3, nc = (t & 7) * 4;
    float4 v = *(const float4*)&W[(size_t)(k0 + kr) * N + n0 + nc];
    T[kr][nc + 0] = f2bf_bits(v.x);
    T[kr][nc + 1] = f2bf_bits(v.y);
    T[kr][nc + 2] = f2bf_bits(v.z);
    T[kr][nc + 3] = f2bf_bits(v.w);
  }
  __syncthreads();
  {
    int nr = t >> 3, kc = (t & 7) * 4;
    ushort4 o;
    o.x = T[kc + 0][nr]; o.y = T[kc + 1][nr];
    o.z = T[kc + 2][nr]; o.w = T[kc + 3][nr];
    *(ushort4*)&WT[(size_t)(n0 + nr) * K + k0 + kc] = o;
  }
}

// ---------------------------------------------------------------------------
// V transpose from fused qkv buffer: qkv[tok][5120 + kvh*128 + d] ->
// VT[(b*8+kvh)*128 + d][1024 s]. 32x32 tiles. grid = (SEQ/32, HD/32, B*NKVH)
// ---------------------------------------------------------------------------
__global__ __launch_bounds__(256)
void vtrans2(const unsigned short* __restrict__ qkv, unsigned short* __restrict__ VT)
{
  __shared__ unsigned short T[32][36];
  const int bh = blockIdx.z;                 // b*8+kvh
  const int s0 = blockIdx.x * 32, d0 = blockIdx.y * 32;
  const int b = bh >> 3, kvh = bh & 7;
  const int t = threadIdx.x;
  {
    int sr = t >> 3, dc = (t & 7) * 4;
    ushort4 v = *(const ushort4*)&qkv[(size_t)(b * SEQ_ + s0 + sr) * QKVW_ + 5120 + kvh * HD_ + d0 + dc];
    T[sr][dc + 0] = v.x; T[sr][dc + 1] = v.y;
    T[sr][dc + 2] = v.z; T[sr][dc + 3] = v.w;
  }
  __syncthreads();
  {
    int dr = t >> 3, sc = (t & 7) * 4;
    ushort4 o;
    o.x = T[sc + 0][dr]; o.y = T[sc + 1][dr];
    o.z = T[sc + 2][dr]; o.w = T[sc + 3][dr];
    *(ushort4*)&VT[((size_t)bh * HD_ + d0 + dr) * SEQ_ + s0 + sc] = o;
  }
}

// ---------------------------------------------------------------------------
// RoPE in place on bf16 pairs inside the fused qkv buffer.
// ---------------------------------------------------------------------------
__global__ __launch_bounds__(256)
void rope2(unsigned int* __restrict__ t, const float* __restrict__ cosf,
           const float* __restrict__ sinf, int shift, int stride_u32, int base_u32)
{
  int idx = blockIdx.x * 256 + threadIdx.x;
  int tok = idx >> shift;
  int rem = idx & ((1 << shift) - 1);
  int d2  = idx & 63;
  int pos = tok & (SEQ_ - 1);
  unsigned int* p = &t[(size_t)tok * stride_u32 + base_u32 + rem];
  unsigned int pv = *p;
  float xe = __uint_as_float(pv << 16);
  float xo = __uint_as_float(pv & 0xFFFF0000u);
  float cv = cosf[pos * 64 + d2];
  float sv = sinf[pos * 64 + d2];
  float oe = xe * cv - xo * sv;
  float oo = xe * sv + xo * cv;
  *p = pack_bf2_rne(oe, oo);
}

// ---------------------------------------------------------------------------
// GEMM v3: C[M][N] = A[M][K] @ B^T (B stored [N][K]), bf16 in, bf16/fp32 out.
//
// Tile 128(M) x 256(N) x 32(K); 8 waves (2M x 4N), per-wave 64x64 (acc = 64
// VGPR). LDS = 3-deep ring x (A 8K + B 16K) = 72 KiB -> TWO blocks/CU
// (144 KiB, 16 waves/CU = 4/SIMD). Cross-block TLP fills the MFMA pipe
// during the other block's ds_read/barrier phase (the round-1 structure was
// 1 block/CU, phase-lockstep -> MfmaUtil capped at ~49% during-busy).
//
// Schedule per K-tile (ONE barrier, ONE counted vmcnt):
//   { ds_read 8 frags from buf[t%3] | issue 3-instr stage of tile t+2 into
//     buf[(t+2)%3] | setprio(1) 16 MFMA setprio(0) | s_waitcnt vmcnt(3)
//     | s_barrier }
// Ring-3 proof: buf[(t+2)%3] == buf[(t-1)%3]; its readers (iteration t-1)
// were sealed by the end-of-(t-1) barrier. vmcnt(3) leaves only tile t+2's
// 3 loads outstanding -> tile t+1 has landed before the barrier.
//
// T2 chunk-XOR swizzle (c ^= (row>>1)&3) applied both-sides: linear gld16
// dest + inverse-swizzled per-lane global source + swizzled ds_read.
// T1 XCD swizzle (grids 768 and 512, both %8==0, both %256==0 -> balanced).
// ---------------------------------------------------------------------------
template<bool OUT_BF16>
__global__ __launch_bounds__(512, 4)
void gemm_bt3(const unsigned short* __restrict__ A,   // [M][K] bf16
              const unsigned short* __restrict__ B,   // [N][K] bf16
              void* __restrict__ Cout, int M, int N, int K)
{
  __shared__ __align__(16) unsigned short As[3][128][32];  // 8 KiB / slot
  __shared__ __align__(16) unsigned short Bs[3][256][32];  // 16 KiB / slot

  const int tid  = threadIdx.x;
  const int w    = tid >> 6;
  const int lane = tid & 63;
  const int l16  = lane & 15;
  const int quad = lane >> 4;
  const int wr   = w >> 2;        // 0..1  (M)
  const int wc   = w & 3;         // 0..3  (N)

  // T1: XCD-aware swizzle (gridDim.x % 8 == 0 at both call sites)
  int wg = blockIdx.x;
  const int q8 = gridDim.x >> 3;
  wg = (wg & 7) * q8 + (wg >> 3);
  const int nbx = N >> 8;
  const int bm = (wg / nbx) * 128;
  const int bn = (wg % nbx) * 256;

  // staging: thread -> row tid>>2, 16B chunk tid&3 (A: 128 rows = 1 instr;
  // B: 256 rows = 2 instrs, second half at row+128 with identical swizzle
  // since 128 == 0 mod 8). Source chunk pre-swizzled so LDS stays linear.
  const int srow   = tid >> 2;
  const int scs    = (tid & 3) ^ ((srow >> 1) & 3);
  const unsigned short* Ag  = &A[(size_t)(bm + srow) * K + scs * 8];
  const unsigned short* Bg  = &B[(size_t)(bn + srow) * K + scs * 8];
  const unsigned short* Bg2 = Bg + (size_t)128 * K;
  char* AsW = (char*)&As[0][0][0] + w * 1024;   // + buf*8192
  char* BsW = (char*)&Bs[0][0][0] + w * 1024;   // + buf*16384 (+8192 for half 2)

  floatx4 acc[4][4];
#pragma unroll
  for (int i = 0; i < 4; i++)
#pragma unroll
    for (int j = 0; j < 4; j++) acc[i][j] = (floatx4){0.f, 0.f, 0.f, 0.f};

  // fragment-read swizzle: row = 64*wr + 16*i + l16 -> (row>>1)&3 = (l16>>1)&3
  const int cfr = quad ^ ((l16 >> 1) & 3);
  const unsigned short* ArF = &As[0][wr * 64][cfr * 8];   // + i*16*32 + l16*32
  const unsigned short* BrF = &Bs[0][wc * 64][cfr * 8];

  const int ntiles = K >> 5;   // 128 for K=4096

  // ---- prologue: stage tiles 0,1 (6 load-instrs/wave); wait tile 0.
  {
    gld16(Ag,       AsW);
    gld16(Bg,       BsW);
    gld16(Bg2,      BsW + 8192);
    gld16(Ag  + 32, AsW + 8192);
    gld16(Bg  + 32, BsW + 16384);
    gld16(Bg2 + 32, BsW + 16384 + 8192);
  }
  asm volatile("s_waitcnt vmcnt(3)" ::: "memory");
  __builtin_amdgcn_s_barrier();

  int buf = 0;     // t % 3
  int pbuf = 2;    // (t+2) % 3
#pragma unroll 1
  for (int t = 0; t < ntiles; t++) {
    // ---- ds_read this tile's fragments (compiler inserts lgkm waits)
    bf16x8 af[4], bfr[4];
    {
      const unsigned short* Ab = ArF + (size_t)buf * (128 * 32) + l16 * 32;
      const unsigned short* Bb = BrF + (size_t)buf * (256 * 32) + l16 * 32;
#pragma unroll
      for (int i = 0; i < 4; i++) af[i]  = *(const bf16x8*)&Ab[i * (16 * 32)];
#pragma unroll
      for (int j = 0; j < 4; j++) bfr[j] = *(const bf16x8*)&Bb[j * (16 * 32)];
    }

    // ---- issue stage of tile t+2 (dummy kt=0 at tail keeps vmcnt uniform;
    //      target buffer is dead either way)
    {
      int pk = t + 2;
      if (pk >= ntiles) pk = 0;
      size_t ko = (size_t)pk << 5;
      gld16(Ag  + ko, AsW + pbuf * 8192);
      gld16(Bg  + ko, BsW + pbuf * 16384);
      gld16(Bg2 + ko, BsW + pbuf * 16384 + 8192);
    }

    __builtin_amdgcn_s_setprio(1);
#pragma unroll
    for (int i = 0; i < 4; i++)
#pragma unroll
      for (int j = 0; j < 4; j++)
        acc[i][j] = __builtin_amdgcn_mfma_f32_16x16x32_bf16(af[i], bfr[j], acc[i][j], 0, 0, 0);
    __builtin_amdgcn_s_setprio(0);

    // tile t+1 landed (only t+2's 3 loads remain in flight), then release
    asm volatile("s_waitcnt vmcnt(3)" ::: "memory");
    __builtin_amdgcn_s_barrier();

    buf  = (buf  == 2) ? 0 : buf + 1;
    pbuf = (pbuf == 2) ? 0 : pbuf + 1;
  }

  // drain dummy tail stages before touching anything else
  asm volatile("s_waitcnt vmcnt(0)" ::: "memory");

  // ---- epilogue: C write
#pragma unroll
  for (int i = 0; i < 4; i++)
#pragma unroll
    for (int j = 0; j < 4; j++)
#pragma unroll
      for (int r = 0; r < 4; r++) {
        size_t row = bm + wr * 64 + i * 16 + quad * 4 + r;
        size_t col = bn + wc * 64 + j * 16 + l16;
        if (OUT_BF16)
          ((unsigned short*)Cout)[row * N + col] = f2bf_bits(acc[i][j][r]);
        else
          ((float*)Cout)[row * N + col] = acc[i][j][r];
      }
}

// ---------------------------------------------------------------------------
// Flash attention v2 (GQA, causal): S^T = K Q^T via mfma_32x32x16 so softmax
// is per-lane-column; O^T = V^T P^T. All LDS XOR-chunk-swizzled (conflict-free).
// Block = 256 q of one (b,h); 4 waves x 64 q; K-tiles of 64 keys.
// ---------------------------------------------------------------------------
__global__ __launch_bounds__(256, 2)
void flash_attn2(const unsigned short* __restrict__ qkv,
                 const unsigned short* __restrict__ vt,
                 unsigned short* __restrict__ o)
{
  __shared__ __align__(16) unsigned short S_[4][8192];  // 64 KiB total
  unsigned short* Ks = &S_[0][0];            // [64 key][128 d], chunk-swizzled ^ (key&15)
  unsigned short* Vs = &S_[1][0];            // [128 d][64 key], chunk-swizzled ^ (d&7)
  // Ps per wave: S_[2..3], 4096 u16 each:   [64 q][64 key], chunk-swizzled ^ (q&7)

  const int qt = blockIdx.x, h = blockIdx.y, b = blockIdx.z;
  const int kvh = h >> 2;
  const int tid = threadIdx.x, w = tid >> 6, lane = tid & 63;
  const int l31 = lane & 31, hi = lane >> 5;
  const int qb = qt * 256, qw = qb + w * 64;
  unsigned short* Ps = &S_[2][0] + w * 4096;

  const float CEXP = (float)(0.08838834764831845 * 1.4426950408889634); // scale*log2(e)

  // ---- Q fragments in registers (B-operand layout: n=l31, k=hi*8+j per 16-k step)
  bf16x8 qf[2][8];
#pragma unroll
  for (int t2 = 0; t2 < 2; t2++) {
    const unsigned short* qrow =
        &qkv[(size_t)(b * SEQ_ + qw + t2 * 32 + l31) * QKVW_ + h * HD_ + hi * 8];
#pragma unroll
    for (int s = 0; s < 8; s++)
      qf[t2][s] = *(const bf16x8*)&qrow[s * 16];
  }

  floatx16 oa[2][4];   // O^T accumulators: [q-subtile][d-tile], col=q=l31
#pragma unroll
  for (int t2 = 0; t2 < 2; t2++)
#pragma unroll
    for (int dt = 0; dt < 4; dt++)
#pragma unroll
      for (int r = 0; r < 16; r++) oa[t2][dt][r] = 0.f;

  float ms[2] = {-3.0e38f, -3.0e38f};  // running max, SCALED (log2) units
  float ls[2] = {0.f, 0.f};

  const int nk = qb + 256;
  const int qmaxw = qw + 63;

  for (int kb_ = 0; kb_ < nk; kb_ += 64) {
    __syncthreads();   // protect LDS from previous iteration's readers
    // ---- stage K tile: 64 keys x 128 d (16 chunks/row)
    {
      const size_t gbase = (size_t)(b * SEQ_ + kb_) * QKVW_ + 4096 + kvh * HD_;
#pragma unroll
      for (int it = 0; it < 4; it++) {
        int idx = it * 256 + tid;
        int key = idx >> 4, c = idx & 15;
        ushortx8 vld = *(const ushortx8*)&qkv[gbase + (size_t)key * QKVW_ + c * 8];
        *(ushortx8*)&Ks[key * 128 + ((c ^ (key & 15)) * 8)] = vld;
      }
      // ---- stage V^T tile: 128 d x 64 keys (8 chunks/row)
      const size_t vbase = ((size_t)(b * NKVH_ + kvh) * HD_) * SEQ_ + kb_;
#pragma unroll
      for (int it = 0; it < 4; it++) {
        int idx = it * 256 + tid;
        int d = idx >> 3, c = idx & 7;
        ushortx8 vld = *(const ushortx8*)&vt[vbase + (size_t)d * SEQ_ + c * 8];
        *(ushortx8*)&Vs[d * 64 + ((c ^ (d & 7)) * 8)] = vld;
      }
    }
    __syncthreads();

    if (kb_ <= qmaxw) {                      // wave has >=1 unmasked key in tile
      const bool needmask = (kb_ + 63 > qw);

#pragma unroll
      for (int t2 = 0; t2 < 2; t2++) {
        // ---- S^T = K @ Q^T : two 32-key C-tiles, rows=keys, cols=queries
        floatx16 sc[2];
#pragma unroll
        for (int r = 0; r < 16; r++) { sc[0][r] = 0.f; sc[1][r] = 0.f; }
#pragma unroll
        for (int s = 0; s < 8; s++) {
          int c = 2 * s + hi;
          bf16x8 k0 = *(const bf16x8*)&Ks[l31 * 128 + ((c ^ (l31 & 15)) * 8)];
          bf16x8 k1 = *(const bf16x8*)&Ks[(32 + l31) * 128 + ((c ^ ((32 + l31) & 15)) * 8)];
          sc[0] = __builtin_amdgcn_mfma_f32_32x32x16_bf16(k0, qf[t2][s], sc[0], 0, 0, 0);
          sc[1] = __builtin_amdgcn_mfma_f32_32x32x16_bf16(k1, qf[t2][s], sc[1], 0, 0, 0);
        }

        // ---- causal mask (row = key = (r&3)+8*(r>>2)+4*hi; col = q = l31)
        if (needmask) {
          const int q = qw + t2 * 32 + l31;
#pragma unroll
          for (int k2 = 0; k2 < 2; k2++)
#pragma unroll
            for (int r = 0; r < 16; r++) {
              int key = kb_ + k2 * 32 + (r & 3) + 8 * (r >> 2) + 4 * hi;
              if (key > q) sc[k2][r] = -3.0e38f;
            }
        }

        // ---- online softmax for this lane's query (32 vals in-lane + xor32)
        float mx0 = sc[0][0], mx1 = sc[0][1];
#pragma unroll
        for (int r = 2; r < 16; r += 2) { mx0 = fmaxf(mx0, sc[0][r]); mx1 = fmaxf(mx1, sc[0][r + 1]); }
#pragma unroll
        for (int r = 0; r < 16; r += 2) { mx0 = fmaxf(mx0, sc[1][r]); mx1 = fmaxf(mx1, sc[1][r + 1]); }
        float mx = fmaxf(mx0, mx1);
        mx = fmaxf(mx, __shfl_xor(mx, 32));
        float mxs = mx * CEXP;
        float mn = fmaxf(ms[t2], mxs);
        float alpha = fast_exp2(ms[t2] - mn);
        ms[t2] = mn;

        float rs0 = 0.f, rs1 = 0.f;
        const int qloc = t2 * 32 + l31;
#pragma unroll
        for (int k2 = 0; k2 < 2; k2++) {
          unsigned int pk[8];
#pragma unroll
          for (int r = 0; r < 16; r += 2) {
            float p0 = fast_exp2(__builtin_fmaf(sc[k2][r],     CEXP, -mn));
            float p1 = fast_exp2(__builtin_fmaf(sc[k2][r + 1], CEXP, -mn));
            rs0 += p0; rs1 += p1;
            pk[r >> 1] = pack_bf2_trunc(p0, p1);
          }
#pragma unroll
          for (int rq = 0; rq < 4; rq++) {
            int keyoff = k2 * 32 + 8 * rq + 4 * hi;
            int c = keyoff >> 3;
            uint2 val = {pk[rq * 2], pk[rq * 2 + 1]};
            *(uint2*)&Ps[qloc * 64 + ((c ^ (qloc & 7)) * 8) + (keyoff & 7)] = val;
          }
        }
        float rs = rs0 + rs1;
        rs += __shfl_xor(rs, 32);
        ls[t2] = ls[t2] * alpha + rs;

        if (__any(alpha != 1.0f)) {
#pragma unroll
          for (int dt = 0; dt < 4; dt++)
#pragma unroll
            for (int r = 0; r < 16; r++) oa[t2][dt][r] *= alpha;
        }
      }

      // ---- O^T += V^T @ P^T  (A-frag V reused across both q-subtiles)
#pragma unroll
      for (int ks = 0; ks < 4; ks++) {
        int c = 2 * ks + hi;
        bf16x8 pf0, pf1;
        {
          int q0l = l31;
          int q1l = 32 + l31;
          pf0 = *(const bf16x8*)&Ps[q0l * 64 + ((c ^ (q0l & 7)) * 8)];
          pf1 = *(const bf16x8*)&Ps[q1l * 64 + ((c ^ (q1l & 7)) * 8)];
        }
#pragma unroll
        for (int dt = 0; dt < 4; dt++) {
          int d = dt * 32 + l31;
          bf16x8 vf = *(const bf16x8*)&Vs[d * 64 + ((c ^ (d & 7)) * 8)];
          oa[0][dt] = __builtin_amdgcn_mfma_f32_32x32x16_bf16(vf, pf0, oa[0][dt], 0, 0, 0);
          oa[1][dt] = __builtin_amdgcn_mfma_f32_32x32x16_bf16(vf, pf1, oa[1][dt], 0, 0, 0);
        }
      }
    }
  }

  // ---- epilogue: normalize, transpose O^T -> O rows via per-wave LDS patch
  __syncthreads();                 // everyone done reading Ks/Vs/Ps
  unsigned short* patch = &S_[w][0];   // [64 q][128 d], chunk-swizzled ^ (q&7)
  float inv[2] = {1.0f / ls[0], 1.0f / ls[1]};
#pragma unroll
  for (int t2 = 0; t2 < 2; t2++) {
    const int qloc = t2 * 32 + l31;
#pragma unroll
    for (int dt = 0; dt < 4; dt++)
#pragma unroll
      for (int rq = 0; rq < 4; rq++) {
        float a0 = oa[t2][dt][rq * 4 + 0] * inv[t2];
        float a1 = oa[t2][dt][rq * 4 + 1] * inv[t2];
        float a2 = oa[t2][dt][rq * 4 + 2] * inv[t2];
        float a3 = oa[t2][dt][rq * 4 + 3] * inv[t2];
        int doff = dt * 32 + 8 * rq + 4 * hi;
        int c = doff >> 3;
        uint2 val = {pack_bf2_rne(a0, a1), pack_bf2_rne(a2, a3)};
        *(uint2*)&patch[qloc * 128 + ((c ^ (qloc & 7)) * 8) + (doff & 7)] = val;
      }
  }
  // in-wave: write -> read dependency handled by compiler waitcnt
#pragma unroll
  for (int it = 0; it < 16; it++) {
    int idx = it * 64 + lane;
    int row = idx >> 4, c = idx & 15;
    int cc = (c & 7) ^ (row & 7);
    int cs = (c & 8) | cc;          // swizzle only low 3 bits (mask was &7)
    ushortx8 vv = *(const ushortx8*)&patch[row * 128 + cs * 8];
    *(ushortx8*)&o[(size_t)(b * SEQ_ + qb + w * 64 + row) * 4096 + h * HD_ + c * 8] = vv;
  }
}

// ---------------------------------------------------------------------------
extern "C" void kernel_launch(void* const* d_in, const int* in_sizes, int n_in,
                              void* d_out, int out_size, void* d_ws, size_t ws_size,
                              hipStream_t stream)
{
  const float* x  = (const float*)d_in[0];
  const float* wq = (const float*)d_in[1];
  const float* wk = (const float*)d_in[2];
  const float* wv = (const float*)d_in[3];
  const float* wo = (const float*)d_in[4];
  const float* fc = (const float*)d_in[5];
  const float* fs = (const float*)d_in[6];
  float* out = (float*)d_out;

  // bf16 workspace layout (2B elems): total 136 MB
  unsigned short* xb    = (unsigned short*)d_ws;                 // 4096x4096 (32MB), reused as ab
  unsigned short* wqkvT = xb    + (size_t)NTOK_ * DIM_;          // 6144x4096 (48MB), reused as woT
  unsigned short* qkvb  = wqkvT + (size_t)QKVW_ * DIM_;          // 4096x6144 (48MB)
  unsigned short* vtb   = qkvb  + (size_t)NTOK_ * QKVW_;         // 8x128x... (8MB)
  unsigned short* ab    = xb;    // alias: xb dead after QKV proj
  unsigned short* woT   = wqkvT; // alias: wqkvT dead after QKV proj

  dim3 blk(256);

  xconv<<<(NTOK_ * DIM_ / 4) / 256, blk, 0, stream>>>(x, xb);
  wtrans<<<dim3(DIM_ / 32, DIM_ / 32), blk, 0, stream>>>(wq, wqkvT, DIM_, DIM_);
  wtrans<<<dim3((NKVH_ * HD_) / 32, DIM_ / 32), blk, 0, stream>>>(wk, wqkvT + (size_t)4096 * DIM_, DIM_, NKVH_ * HD_);
  wtrans<<<dim3((NKVH_ * HD_) / 32, DIM_ / 32), blk, 0, stream>>>(wv, wqkvT + (size_t)5120 * DIM_, DIM_, NKVH_ * HD_);

  // fused QKV projection: 128x256 tiles, 32x24 = 768 wgs = 3 balanced rounds
  gemm_bt3<true><<<dim3((NTOK_ / 128) * (QKVW_ / 256)), dim3(512), 0, stream>>>(
      xb, wqkvT, qkvb, NTOK_, QKVW_, DIM_);

  wtrans<<<dim3(DIM_ / 32, DIM_ / 32), blk, 0, stream>>>(wo, woT, DIM_, DIM_);  // aliases wqkvT: after QKV GEMM

  // RoPE on Q (2048 u32/token) and K (512 u32/token at base 2048)
  rope2<<<(NTOK_ * 2048) / 256, blk, 0, stream>>>((unsigned int*)qkvb, fc, fs, 11, 3072, 0);
  rope2<<<(NTOK_ * 512) / 256, blk, 0, stream>>>((unsigned int*)qkvb, fc, fs, 9, 3072, 2048);

  vtrans2<<<dim3(SEQ_ / 32, HD_ / 32, BSZ_ * NKVH_), blk, 0, stream>>>(qkvb, vtb);

  flash_attn2<<<dim3(SEQ_ / 256, NH_, BSZ_), blk, 0, stream>>>(qkvb, vtb, ab);

  // output projection: 128x256 tiles, 32x16 = 512 wgs = 2 balanced rounds
  gemm_bt3<false><<<dim3((NTOK_ / 128) * (DIM_ / 256)), dim3(512), 0, stream>>>(
      ab, woT, out, NTOK_, DIM_, DIM_);
}

// Round 3
// 750.207 us; speedup vs baseline: 1.0825x; 1.0825x over previous
//
#include <hip/hip_runtime.h>

#define BSZ_  4
#define SEQ_  1024
#define NH_   32
#define NKVH_ 8
#define HD_   128
#define DIM_  4096
#define NTOK_ (BSZ_ * SEQ_)   // 4096 tokens
#define QKVW_ 6144            // fused QKV output width (u16 elems per token)

typedef float  floatx4  __attribute__((ext_vector_type(4)));
typedef float  floatx16 __attribute__((ext_vector_type(16)));
typedef __bf16 bf16x8   __attribute__((ext_vector_type(8)));
typedef unsigned short ushortx8 __attribute__((ext_vector_type(8)));

__device__ __forceinline__ float fast_exp2(float x) {
  return __builtin_amdgcn_exp2f(x);   // v_exp_f32 (computes 2^x natively)
}

__device__ __forceinline__ unsigned short f2bf_bits(float f) {
  unsigned int u = __float_as_uint(f);
  u += 0x7FFFu + ((u >> 16) & 1u);   // round-to-nearest-even
  return (unsigned short)(u >> 16);
}
__device__ __forceinline__ unsigned int pack_bf2_rne(float lo, float hi_) {
  return (unsigned int)f2bf_bits(lo) | ((unsigned int)f2bf_bits(hi_) << 16);
}
// truncating pack of two fp32 -> bf16x2 (one v_perm_b32)
__device__ __forceinline__ unsigned int pack_bf2_trunc(float lo, float hi_) {
  return __builtin_amdgcn_perm(__float_as_uint(hi_), __float_as_uint(lo), 0x07060302u);
}

// async global->LDS, 16B per lane; LDS dest = wave-uniform base + lane*16
__device__ __forceinline__ void gld16(const void* g, void* l) {
  __builtin_amdgcn_global_load_lds(
      (const __attribute__((address_space(1))) void*)g,
      (__attribute__((address_space(3))) void*)l, 16, 0, 0);
}

// ---------------------------------------------------------------------------
// fp32 -> bf16 convert (contiguous).
// ---------------------------------------------------------------------------
__global__ __launch_bounds__(256)
void xconv(const float* __restrict__ X, unsigned short* __restrict__ XB)
{
  size_t i = ((size_t)blockIdx.x * 256 + threadIdx.x) * 4;
  float4 v = *(const float4*)&X[i];
  ushort4 o;
  o.x = f2bf_bits(v.x); o.y = f2bf_bits(v.y);
  o.z = f2bf_bits(v.z); o.w = f2bf_bits(v.w);
  *(ushort4*)&XB[i] = o;
}

// ---------------------------------------------------------------------------
// Weight transpose-convert: W[K][N] fp32 -> WT[N][K] bf16. 32x32 tiles.
// ---------------------------------------------------------------------------
__global__ __launch_bounds__(256)
void wtrans(const float* __restrict__ W, unsigned short* __restrict__ WT,
            int K, int N)
{
  __shared__ unsigned short T[32][36];
  const int k0 = blockIdx.y * 32, n0 = blockIdx.x * 32;
  const int t = threadIdx.x;
  {
    int kr = t >> 3, nc = (t & 7) * 4;
    float4 v = *(const float4*)&W[(size_t)(k0 + kr) * N + n0 + nc];
    T[kr][nc + 0] = f2bf_bits(v.x);
    T[kr][nc + 1] = f2bf_bits(v.y);
    T[kr][nc + 2] = f2bf_bits(v.z);
    T[kr][nc + 3] = f2bf_bits(v.w);
  }
  __syncthreads();
  {
    int nr = t >> 3, kc = (t & 7) * 4;
    ushort4 o;
    o.x = T[kc + 0][nr]; o.y = T[kc + 1][nr];
    o.z = T[kc + 2][nr]; o.w = T[kc + 3][nr];
    *(ushort4*)&WT[(size_t)(n0 + nr) * K + k0 + kc] = o;
  }
}

// ---------------------------------------------------------------------------
// V transpose from fused qkv buffer: qkv[tok][5120 + kvh*128 + d] ->
// VT[(b*8+kvh)*128 + d][1024 s]. 32x32 tiles. grid = (SEQ/32, HD/32, B*NKVH)
// ---------------------------------------------------------------------------
__global__ __launch_bounds__(256)
void vtrans2(const unsigned short* __restrict__ qkv, unsigned short* __restrict__ VT)
{
  __shared__ unsigned short T[32][36];
  const int bh = blockIdx.z;                 // b*8+kvh
  const int s0 = blockIdx.x * 32, d0 = blockIdx.y * 32;
  const int b = bh >> 3, kvh = bh & 7;
  const int t = threadIdx.x;
  {
    int sr = t >> 3, dc = (t & 7) * 4;
    ushort4 v = *(const ushort4*)&qkv[(size_t)(b * SEQ_ + s0 + sr) * QKVW_ + 5120 + kvh * HD_ + d0 + dc];
    T[sr][dc + 0] = v.x; T[sr][dc + 1] = v.y;
    T[sr][dc + 2] = v.z; T[sr][dc + 3] = v.w;
  }
  __syncthreads();
  {
    int dr = t >> 3, sc = (t & 7) * 4;
    ushort4 o;
    o.x = T[sc + 0][dr]; o.y = T[sc + 1][dr];
    o.z = T[sc + 2][dr]; o.w = T[sc + 3][dr];
    *(ushort4*)&VT[((size_t)bh * HD_ + d0 + dr) * SEQ_ + s0 + sc] = o;
  }
}

// ---------------------------------------------------------------------------
// RoPE in place on bf16 pairs inside the fused qkv buffer.
// ---------------------------------------------------------------------------
__global__ __launch_bounds__(256)
void rope2(unsigned int* __restrict__ t, const float* __restrict__ cosf,
           const float* __restrict__ sinf, int shift, int stride_u32, int base_u32)
{
  int idx = blockIdx.x * 256 + threadIdx.x;
  int tok = idx >> shift;
  int rem = idx & ((1 << shift) - 1);
  int d2  = idx & 63;
  int pos = tok & (SEQ_ - 1);
  unsigned int* p = &t[(size_t)tok * stride_u32 + base_u32 + rem];
  unsigned int pv = *p;
  float xe = __uint_as_float(pv << 16);
  float xo = __uint_as_float(pv & 0xFFFF0000u);
  float cv = cosf[pos * 64 + d2];
  float sv = sinf[pos * 64 + d2];
  float oe = xe * cv - xo * sv;
  float oo = xe * sv + xo * cv;
  *p = pack_bf2_rne(oe, oo);
}

// ---------------------------------------------------------------------------
// GEMM v4: C[M][N] = A[M][K] @ B^T (B stored [N][K]), bf16 in, bf16/fp32 out.
//
// Tile 256x256x32; 8 waves (2M x 4N), per-wave 128x64 (acc 8x4 floatx4).
// LDS = 4-deep ring x (A 16K + B 16K) = 128 KiB, 1 block/CU.
//
// ONE barrier + ONE counted vmcnt per K-tile; register-prefetched frags.
// Sub-iteration s:
//   stage(s+3) into buf (s+3)&3        // 4 gld16
//   s_waitcnt vmcnt(8)                 // 12 outstanding -> tile s+1 landed
//   s_waitcnt lgkmcnt(0)               // my frags(s) loaded; buf reads drained
//   s_barrier; sched_barrier(0)
//   ds_read frags(s+1)                 // 12 x b128, into the spare reg set
//   setprio(1); 32 MFMA on frags(s); setprio(0)
// Race proof:
//  - stage into buf (s+3)&3 == buf (s-1)&3: last reads of that buf (frags(s-1),
//    issued sub s-2) were drained by sub s-1's lgkmcnt(0)+barrier, and the
//    stage is issued after that barrier in every wave's program order.
//  - vmcnt(8) before the barrier in EVERY wave -> tile s+1's DMA writes have
//    landed chip-wide before any post-barrier ds_read touches them.
//  - frags(s+1) reads complete before MFMA(s+1) via sub s+1's lgkmcnt(0).
// Tail: dummy stages (kt=0) into dead buffers keep vmcnt counts uniform.
//
// T2 chunk-XOR swizzle (c ^= (row>>1)&3): linear gld16 dest + inverse-swizzled
// per-lane global source + swizzled ds_read. T1 XCD swizzle (grid %8==0).
// ---------------------------------------------------------------------------
template<bool OUT_BF16>
__global__ __launch_bounds__(512, 2)
void gemm_v4(const unsigned short* __restrict__ A,   // [M][K] bf16
             const unsigned short* __restrict__ B,   // [N][K] bf16
             void* __restrict__ Cout, int M, int N, int K)
{
  __shared__ __align__(16) unsigned short As[4][256][32];  // 16 KiB / slot
  __shared__ __align__(16) unsigned short Bs[4][256][32];

  const int tid  = threadIdx.x;
  const int w    = tid >> 6;
  const int lane = tid & 63;
  const int l16  = lane & 15;
  const int quad = lane >> 4;
  const int wr   = w >> 2;        // 0..1  (M)
  const int wc   = w & 3;         // 0..3  (N)

  // T1: XCD-aware swizzle (gridDim.x % 8 == 0 at both call sites)
  int wg = blockIdx.x;
  const int q8 = gridDim.x >> 3;
  wg = (wg & 7) * q8 + (wg >> 3);
  const int nbx = N >> 8;
  const int bm = (wg / nbx) * 256;
  const int bn = (wg % nbx) * 256;

  // staging: wave w instr i covers rows [i*128 + w*16, +16), lane -> row
  // w*16 + (lane>>2), chunk lane&3; source chunk pre-swizzled (LDS linear).
  const int srow = w * 16 + (lane >> 2);              // 0..127
  const int scs  = (lane & 3) ^ ((srow >> 1) & 3);    // (srow+128 gives same)
  const unsigned short* Ag = &A[(size_t)(bm + srow) * K + scs * 8];
  const unsigned short* Bg = &B[(size_t)(bn + srow) * K + scs * 8];
  const size_t half = (size_t)128 * K;
  char* AsW = (char*)&As[0][0][0] + w * 1024;
  char* BsW = (char*)&Bs[0][0][0] + w * 1024;

  const int ntiles = K >> 5;   // 128 for K=4096

  auto stage = [&](int kt, int buf) {
    size_t ko = (size_t)kt << 5;
    gld16(Ag + ko,        AsW + buf * 16384);
    gld16(Ag + ko + half, AsW + buf * 16384 + 8192);
    gld16(Bg + ko,        BsW + buf * 16384);
    gld16(Bg + ko + half, BsW + buf * 16384 + 8192);
  };

  floatx4 acc[8][4];
#pragma unroll
  for (int i = 0; i < 8; i++)
#pragma unroll
    for (int j = 0; j < 4; j++) acc[i][j] = (floatx4){0.f, 0.f, 0.f, 0.f};

  // fragment-read swizzle: row = (wr*128|wc*64) + 16*i + l16 -> (row>>1)&3
  // depends only on l16
  const int cfr = quad ^ ((l16 >> 1) & 3);

  auto ldfrags = [&](int kt, bf16x8* aF, bf16x8* bF) {
    const int buf = kt & 3;
    const unsigned short* Ab = &As[buf][wr * 128 + l16][cfr * 8];
    const unsigned short* Bb = &Bs[buf][wc * 64  + l16][cfr * 8];
#pragma unroll
    for (int i = 0; i < 8; i++) aF[i] = *(const bf16x8*)&Ab[i * (16 * 32)];
#pragma unroll
    for (int j = 0; j < 4; j++) bF[j] = *(const bf16x8*)&Bb[j * (16 * 32)];
  };

  auto domfma = [&](bf16x8* aF, bf16x8* bF) {
    __builtin_amdgcn_s_setprio(1);
#pragma unroll
    for (int i = 0; i < 8; i++)
#pragma unroll
      for (int j = 0; j < 4; j++)
        acc[i][j] = __builtin_amdgcn_mfma_f32_16x16x32_bf16(aF[i], bF[j], acc[i][j], 0, 0, 0);
    __builtin_amdgcn_s_setprio(0);
  };

  auto syncstep = [&]() {
    asm volatile("s_waitcnt vmcnt(8)" ::: "memory");
    asm volatile("s_waitcnt lgkmcnt(0)" ::: "memory");
    __builtin_amdgcn_s_barrier();
    __builtin_amdgcn_sched_barrier(0);
  };

  bf16x8 aF0[8], bF0[4], aF1[8], bF1[4];

  // ---- prologue: stage tiles 0..2 (12 loads); tile 0 landed at vmcnt(8)
  stage(0, 0); stage(1, 1); stage(2, 2);
  syncstep();
  ldfrags(0, aF0, bF0);

#pragma unroll 1
  for (int t = 0; t < ntiles; t += 2) {
    // ---- sub-iteration s = t
    {
      int pk = t + 3 < ntiles ? t + 3 : 0;
      stage(pk, (t + 3) & 3);
    }
    syncstep();                          // tile t+1 landed; frags(t) in regs
    ldfrags(t + 1, aF1, bF1);            // t+1 <= ntiles-1 always
    domfma(aF0, bF0);                    // MFMA(t)

    // ---- sub-iteration s = t+1
    {
      int pk = t + 4 < ntiles ? t + 4 : 0;
      stage(pk, (t + 4) & 3);
    }
    syncstep();                          // tile t+2 landed (or dummy)
    {
      int kt2 = t + 2 < ntiles ? t + 2 : 0;   // tail: dummy read, dead regs
      ldfrags(kt2, aF0, bF0);
    }
    domfma(aF1, bF1);                    // MFMA(t+1)
  }

  asm volatile("s_waitcnt vmcnt(0)" ::: "memory");   // drain dummy stages

  // ---- epilogue: C write
#pragma unroll
  for (int i = 0; i < 8; i++)
#pragma unroll
    for (int j = 0; j < 4; j++)
#pragma unroll
      for (int r = 0; r < 4; r++) {
        size_t row = bm + wr * 128 + i * 16 + quad * 4 + r;
        size_t col = bn + wc * 64 + j * 16 + l16;
        if (OUT_BF16)
          ((unsigned short*)Cout)[row * N + col] = f2bf_bits(acc[i][j][r]);
        else
          ((float*)Cout)[row * N + col] = acc[i][j][r];
      }
}

// ---------------------------------------------------------------------------
// Flash attention v2 (GQA, causal): S^T = K Q^T via mfma_32x32x16 so softmax
// is per-lane-column; O^T = V^T P^T. All LDS XOR-chunk-swizzled (conflict-free).
// Block = 256 q of one (b,h); 4 waves x 64 q; K-tiles of 64 keys.
// ---------------------------------------------------------------------------
__global__ __launch_bounds__(256, 2)
void flash_attn2(const unsigned short* __restrict__ qkv,
                 const unsigned short* __restrict__ vt,
                 unsigned short* __restrict__ o)
{
  __shared__ __align__(16) unsigned short S_[4][8192];  // 64 KiB total
  unsigned short* Ks = &S_[0][0];            // [64 key][128 d], chunk-swizzled ^ (key&15)
  unsigned short* Vs = &S_[1][0];            // [128 d][64 key], chunk-swizzled ^ (d&7)
  // Ps per wave: S_[2..3], 4096 u16 each:   [64 q][64 key], chunk-swizzled ^ (q&7)

  const int qt = blockIdx.x, h = blockIdx.y, b = blockIdx.z;
  const int kvh = h >> 2;
  const int tid = threadIdx.x, w = tid >> 6, lane = tid & 63;
  const int l31 = lane & 31, hi = lane >> 5;
  const int qb = qt * 256, qw = qb + w * 64;
  unsigned short* Ps = &S_[2][0] + w * 4096;

  const float CEXP = (float)(0.08838834764831845 * 1.4426950408889634); // scale*log2(e)

  // ---- Q fragments in registers (B-operand layout: n=l31, k=hi*8+j per 16-k step)
  bf16x8 qf[2][8];
#pragma unroll
  for (int t2 = 0; t2 < 2; t2++) {
    const unsigned short* qrow =
        &qkv[(size_t)(b * SEQ_ + qw + t2 * 32 + l31) * QKVW_ + h * HD_ + hi * 8];
#pragma unroll
    for (int s = 0; s < 8; s++)
      qf[t2][s] = *(const bf16x8*)&qrow[s * 16];
  }

  floatx16 oa[2][4];   // O^T accumulators: [q-subtile][d-tile], col=q=l31
#pragma unroll
  for (int t2 = 0; t2 < 2; t2++)
#pragma unroll
    for (int dt = 0; dt < 4; dt++)
#pragma unroll
      for (int r = 0; r < 16; r++) oa[t2][dt][r] = 0.f;

  float ms[2] = {-3.0e38f, -3.0e38f};  // running max, SCALED (log2) units
  float ls[2] = {0.f, 0.f};

  const int nk = qb + 256;
  const int qmaxw = qw + 63;

  for (int kb_ = 0; kb_ < nk; kb_ += 64) {
    __syncthreads();   // protect LDS from previous iteration's readers
    // ---- stage K tile: 64 keys x 128 d (16 chunks/row)
    {
      const size_t gbase = (size_t)(b * SEQ_ + kb_) * QKVW_ + 4096 + kvh * HD_;
#pragma unroll
      for (int it = 0; it < 4; it++) {
        int idx = it * 256 + tid;
        int key = idx >> 4, c = idx & 15;
        ushortx8 vld = *(const ushortx8*)&qkv[gbase + (size_t)key * QKVW_ + c * 8];
        *(ushortx8*)&Ks[key * 128 + ((c ^ (key & 15)) * 8)] = vld;
      }
      // ---- stage V^T tile: 128 d x 64 keys (8 chunks/row)
      const size_t vbase = ((size_t)(b * NKVH_ + kvh) * HD_) * SEQ_ + kb_;
#pragma unroll
      for (int it = 0; it < 4; it++) {
        int idx = it * 256 + tid;
        int d = idx >> 3, c = idx & 7;
        ushortx8 vld = *(const ushortx8*)&vt[vbase + (size_t)d * SEQ_ + c * 8];
        *(ushortx8*)&Vs[d * 64 + ((c ^ (d & 7)) * 8)] = vld;
      }
    }
    __syncthreads();

    if (kb_ <= qmaxw) {                      // wave has >=1 unmasked key in tile
      const bool needmask = (kb_ + 63 > qw);

#pragma unroll
      for (int t2 = 0; t2 < 2; t2++) {
        // ---- S^T = K @ Q^T : two 32-key C-tiles, rows=keys, cols=queries
        floatx16 sc[2];
#pragma unroll
        for (int r = 0; r < 16; r++) { sc[0][r] = 0.f; sc[1][r] = 0.f; }
#pragma unroll
        for (int s = 0; s < 8; s++) {
          int c = 2 * s + hi;
          bf16x8 k0 = *(const bf16x8*)&Ks[l31 * 128 + ((c ^ (l31 & 15)) * 8)];
          bf16x8 k1 = *(const bf16x8*)&Ks[(32 + l31) * 128 + ((c ^ ((32 + l31) & 15)) * 8)];
          sc[0] = __builtin_amdgcn_mfma_f32_32x32x16_bf16(k0, qf[t2][s], sc[0], 0, 0, 0);
          sc[1] = __builtin_amdgcn_mfma_f32_32x32x16_bf16(k1, qf[t2][s], sc[1], 0, 0, 0);
        }

        // ---- causal mask (row = key = (r&3)+8*(r>>2)+4*hi; col = q = l31)
        if (needmask) {
          const int q = qw + t2 * 32 + l31;
#pragma unroll
          for (int k2 = 0; k2 < 2; k2++)
#pragma unroll
            for (int r = 0; r < 16; r++) {
              int key = kb_ + k2 * 32 + (r & 3) + 8 * (r >> 2) + 4 * hi;
              if (key > q) sc[k2][r] = -3.0e38f;
            }
        }

        // ---- online softmax for this lane's query (32 vals in-lane + xor32)
        float mx0 = sc[0][0], mx1 = sc[0][1];
#pragma unroll
        for (int r = 2; r < 16; r += 2) { mx0 = fmaxf(mx0, sc[0][r]); mx1 = fmaxf(mx1, sc[0][r + 1]); }
#pragma unroll
        for (int r = 0; r < 16; r += 2) { mx0 = fmaxf(mx0, sc[1][r]); mx1 = fmaxf(mx1, sc[1][r + 1]); }
        float mx = fmaxf(mx0, mx1);
        mx = fmaxf(mx, __shfl_xor(mx, 32));
        float mxs = mx * CEXP;
        float mn = fmaxf(ms[t2], mxs);
        float alpha = fast_exp2(ms[t2] - mn);
        ms[t2] = mn;

        float rs0 = 0.f, rs1 = 0.f;
        const int qloc = t2 * 32 + l31;
#pragma unroll
        for (int k2 = 0; k2 < 2; k2++) {
          unsigned int pk[8];
#pragma unroll
          for (int r = 0; r < 16; r += 2) {
            float p0 = fast_exp2(__builtin_fmaf(sc[k2][r],     CEXP, -mn));
            float p1 = fast_exp2(__builtin_fmaf(sc[k2][r + 1], CEXP, -mn));
            rs0 += p0; rs1 += p1;
            pk[r >> 1] = pack_bf2_trunc(p0, p1);
          }
#pragma unroll
          for (int rq = 0; rq < 4; rq++) {
            int keyoff = k2 * 32 + 8 * rq + 4 * hi;
            int c = keyoff >> 3;
            uint2 val = {pk[rq * 2], pk[rq * 2 + 1]};
            *(uint2*)&Ps[qloc * 64 + ((c ^ (qloc & 7)) * 8) + (keyoff & 7)] = val;
          }
        }
        float rs = rs0 + rs1;
        rs += __shfl_xor(rs, 32);
        ls[t2] = ls[t2] * alpha + rs;

        if (__any(alpha != 1.0f)) {
#pragma unroll
          for (int dt = 0; dt < 4; dt++)
#pragma unroll
            for (int r = 0; r < 16; r++) oa[t2][dt][r] *= alpha;
        }
      }

      // ---- O^T += V^T @ P^T  (A-frag V reused across both q-subtiles)
#pragma unroll
      for (int ks = 0; ks < 4; ks++) {
        int c = 2 * ks + hi;
        bf16x8 pf0, pf1;
        {
          int q0l = l31;
          int q1l = 32 + l31;
          pf0 = *(const bf16x8*)&Ps[q0l * 64 + ((c ^ (q0l & 7)) * 8)];
          pf1 = *(const bf16x8*)&Ps[q1l * 64 + ((c ^ (q1l & 7)) * 8)];
        }
#pragma unroll
        for (int dt = 0; dt < 4; dt++) {
          int d = dt * 32 + l31;
          bf16x8 vf = *(const bf16x8*)&Vs[d * 64 + ((c ^ (d & 7)) * 8)];
          oa[0][dt] = __builtin_amdgcn_mfma_f32_32x32x16_bf16(vf, pf0, oa[0][dt], 0, 0, 0);
          oa[1][dt] = __builtin_amdgcn_mfma_f32_32x32x16_bf16(vf, pf1, oa[1][dt], 0, 0, 0);
        }
      }
    }
  }

  // ---- epilogue: normalize, transpose O^T -> O rows via per-wave LDS patch
  __syncthreads();                 // everyone done reading Ks/Vs/Ps
  unsigned short* patch = &S_[w][0];   // [64 q][128 d], chunk-swizzled ^ (q&7)
  float inv[2] = {1.0f / ls[0], 1.0f / ls[1]};
#pragma unroll
  for (int t2 = 0; t2 < 2; t2++) {
    const int qloc = t2 * 32 + l31;
#pragma unroll
    for (int dt = 0; dt < 4; dt++)
#pragma unroll
      for (int rq = 0; rq < 4; rq++) {
        float a0 = oa[t2][dt][rq * 4 + 0] * inv[t2];
        float a1 = oa[t2][dt][rq * 4 + 1] * inv[t2];
        float a2 = oa[t2][dt][rq * 4 + 2] * inv[t2];
        float a3 = oa[t2][dt][rq * 4 + 3] * inv[t2];
        int doff = dt * 32 + 8 * rq + 4 * hi;
        int c = doff >> 3;
        uint2 val = {pack_bf2_rne(a0, a1), pack_bf2_rne(a2, a3)};
        *(uint2*)&patch[qloc * 128 + ((c ^ (qloc & 7)) * 8) + (doff & 7)] = val;
      }
  }
  // in-wave: write -> read dependency handled by compiler waitcnt
#pragma unroll
  for (int it = 0; it < 16; it++) {
    int idx = it * 64 + lane;
    int row = idx >> 4, c = idx & 15;
    int cc = (c & 7) ^ (row & 7);
    int cs = (c & 8) | cc;          // swizzle only low 3 bits (mask was &7)
    ushortx8 vv = *(const ushortx8*)&patch[row * 128 + cs * 8];
    *(ushortx8*)&o[(size_t)(b * SEQ_ + qb + w * 64 + row) * 4096 + h * HD_ + c * 8] = vv;
  }
}

// ---------------------------------------------------------------------------
extern "C" void kernel_launch(void* const* d_in, const int* in_sizes, int n_in,
                              void* d_out, int out_size, void* d_ws, size_t ws_size,
                              hipStream_t stream)
{
  const float* x  = (const float*)d_in[0];
  const float* wq = (const float*)d_in[1];
  const float* wk = (const float*)d_in[2];
  const float* wv = (const float*)d_in[3];
  const float* wo = (const float*)d_in[4];
  const float* fc = (const float*)d_in[5];
  const float* fs = (const float*)d_in[6];
  float* out = (float*)d_out;

  // bf16 workspace layout (2B elems): total 136 MB
  unsigned short* xb    = (unsigned short*)d_ws;                 // 4096x4096 (32MB), reused as ab
  unsigned short* wqkvT = xb    + (size_t)NTOK_ * DIM_;          // 6144x4096 (48MB), reused as woT
  unsigned short* qkvb  = wqkvT + (size_t)QKVW_ * DIM_;          // 4096x6144 (48MB)
  unsigned short* vtb   = qkvb  + (size_t)NTOK_ * QKVW_;         // 8x128x... (8MB)
  unsigned short* ab    = xb;    // alias: xb dead after QKV proj
  unsigned short* woT   = wqkvT; // alias: wqkvT dead after QKV proj

  dim3 blk(256);

  xconv<<<(NTOK_ * DIM_ / 4) / 256, blk, 0, stream>>>(x, xb);
  wtrans<<<dim3(DIM_ / 32, DIM_ / 32), blk, 0, stream>>>(wq, wqkvT, DIM_, DIM_);
  wtrans<<<dim3((NKVH_ * HD_) / 32, DIM_ / 32), blk, 0, stream>>>(wk, wqkvT + (size_t)4096 * DIM_, DIM_, NKVH_ * HD_);
  wtrans<<<dim3((NKVH_ * HD_) / 32, DIM_ / 32), blk, 0, stream>>>(wv, wqkvT + (size_t)5120 * DIM_, DIM_, NKVH_ * HD_);

  // fused QKV projection: 256x256 tiles, 16x24 = 384 wgs
  gemm_v4<true><<<dim3((NTOK_ / 256) * (QKVW_ / 256)), dim3(512), 0, stream>>>(
      xb, wqkvT, qkvb, NTOK_, QKVW_, DIM_);

  wtrans<<<dim3(DIM_ / 32, DIM_ / 32), blk, 0, stream>>>(wo, woT, DIM_, DIM_);  // aliases wqkvT: after QKV GEMM

  // RoPE on Q (2048 u32/token) and K (512 u32/token at base 2048)
  rope2<<<(NTOK_ * 2048) / 256, blk, 0, stream>>>((unsigned int*)qkvb, fc, fs, 11, 3072, 0);
  rope2<<<(NTOK_ * 512) / 256, blk, 0, stream>>>((unsigned int*)qkvb, fc, fs, 9, 3072, 2048);

  vtrans2<<<dim3(SEQ_ / 32, HD_ / 32, BSZ_ * NKVH_), blk, 0, stream>>>(qkvb, vtb);

  flash_attn2<<<dim3(SEQ_ / 256, NH_, BSZ_), blk, 0, stream>>>(qkvb, vtb, ab);

  // output projection: 256x256 tiles, 16x16 = 256 wgs (perfect packing)
  gemm_v4<false><<<dim3((NTOK_ / 256) * (DIM_ / 256)), dim3(512), 0, stream>>>(
      ab, woT, out, NTOK_, DIM_, DIM_);
}